// Round 22
// baseline (333.531 us; speedup 1.0000x reference)
//
#include <hip/hip_runtime.h>

#define NN 100000        // nodes
#define NE 1600000       // edges
#define NRL 3            // relations
#define NG 1024          // graphs
#define NBUCK 782        // ceil(NN/128) buckets of 128 nodes
#define NXCD 8
#define PSTRIDE 384      // slots per (bucket, xcd): mean 256, sigma 16 -> +8 sigma
#define BSLOTS (NXCD * PSTRIDE)   // 3072 slots per bucket
#define NKEY 384         // 128 nodes * 3 rel
#define OSTRIDE 392      // u16 offsets per bucket (384 starts + total, padded)
#define EB 4096          // edges per k_bucket block
#define NB 32            // nodes per fused agg+transform block
#define KST 264          // LDS K row stride in shorts (528B: 16B-aligned, 2-way banks)

typedef __attribute__((ext_vector_type(8))) short bf16x8;
typedef __attribute__((ext_vector_type(4))) float f32x4;
typedef __attribute__((ext_vector_type(2))) float f32x2;

__device__ __forceinline__ int xcd_id() {
    unsigned int x;
    asm volatile("s_getreg_b32 %0, hwreg(HW_REG_XCC_ID)" : "=s"(x));
    return (int)(x & 7);
}

// f32 -> bf16 with round-to-nearest-even
__device__ __forceinline__ unsigned short f2bf(float f) {
    unsigned u = __float_as_uint(f);
    unsigned r = (u + 0x7fffu + ((u >> 16) & 1u)) >> 16;
    return (unsigned short)r;
}

// ---------------- embed + lin0 + relu (bf16 mirror only) ----------------
__global__ void k_embed(const int* __restrict__ x_idx,
                        const float* __restrict__ semb, const float* __restrict__ cemb,
                        const float* __restrict__ w, const float* __restrict__ b,
                        unsigned short* __restrict__ xbf) {
    __shared__ float s_w[16 * 64];
    __shared__ float s_se[64], s_ce[64], s_b[64];
    int t = threadIdx.x;
    for (int i = t; i < 16 * 64; i += 256) s_w[i] = w[i];
    if (t < 64) { s_se[t] = semb[t]; s_ce[t] = cemb[t]; s_b[t] = b[t]; }
    __syncthreads();
    int gid = blockIdx.x * 256 + t;           // grid exactly NN*64/256
    int v = gid >> 6, h = gid & 63;
    int si = x_idx[2 * v], ci = x_idx[2 * v + 1];
    float acc = s_b[h];
#pragma unroll
    for (int d = 0; d < 8; ++d) acc += s_se[si * 8 + d] * s_w[d * 64 + h];
#pragma unroll
    for (int d = 0; d < 8; ++d) acc += s_ce[ci * 8 + d] * s_w[(8 + d) * 64 + h];
    xbf[gid] = f2bf(fmaxf(acc, 0.f));
}

// ---------------- bucket build: LDS-binned, run-coalesced writeback ----------------
// rec = src (17b) | rel<<17 (2b) | (dst&127)<<19 (7b)
__global__ __launch_bounds__(256) void k_bucket(
        const int* __restrict__ ei, const int* __restrict__ et,
        int* __restrict__ bcnt, unsigned int* __restrict__ arena) {
    __shared__ unsigned int   s_srt[EB];
    __shared__ unsigned short s_skey[EB];
    __shared__ int s_hist[NBUCK], s_start[NBUCK + 1], s_base[NBUCK], s_pos[NBUCK];
    int t = threadIdx.x;
    int e0 = blockIdx.x * EB;
    int n = NE - e0; if (n > EB) n = EB;
    int p = xcd_id();                              // block-uniform (block lives on 1 CU)

    for (int i = t; i < NBUCK; i += 256) s_hist[i] = 0;
    __syncthreads();

    // pass 1: histogram buckets
    for (int i = t; i < n; i += 256) {
        int dst = __builtin_nontemporal_load(ei + NE + e0 + i);
        atomicAdd(&s_hist[dst >> 7], 1);
    }
    __syncthreads();
    if (t == 0) {
        int run = 0;
#pragma unroll 8
        for (int k = 0; k < NBUCK; ++k) { s_start[k] = run; run += s_hist[k]; }
        s_start[NBUCK] = run;
    }
    __syncthreads();
    // reserve global runs (one atomic per non-empty bucket)
    for (int k = t; k < NBUCK; k += 256) {
        s_pos[k] = s_start[k];
        s_base[k] = (s_hist[k] > 0) ? atomicAdd(&bcnt[k * NXCD + p], s_hist[k]) : 0;
    }
    __syncthreads();

    // pass 2: scatter records into LDS in bucket-sorted order
    for (int i = t; i < n; i += 256) {
        int e = e0 + i;
        int src = __builtin_nontemporal_load(ei + e);
        int dst = __builtin_nontemporal_load(ei + NE + e);
        int rel = __builtin_nontemporal_load(et + e);
        int key = dst >> 7;
        unsigned int rec = (unsigned int)src | ((unsigned int)rel << 17) |
                           ((unsigned int)(dst & 127) << 19);
        int q = atomicAdd(&s_pos[key], 1);
        s_srt[q] = rec;
        s_skey[q] = (unsigned short)key;
    }
    __syncthreads();

    // coalesced writeback: sorted index i -> arena[(key,xcd) partition, base + rank]
    for (int i = t; i < n; i += 256) {
        int key = (int)s_skey[i];
        int off = s_base[key] + (i - s_start[key]);
        if (off < PSTRIDE)
            arena[((size_t)key * NXCD + p) * PSTRIDE + off] = s_srt[i];
    }
}

// ---------------- per-bucket LDS counting sort: 8 partitions -> sorted offsets ----------------
// key = dstlo*3 + rel (384 keys). Stores PRE-SCALED byte offsets (src<<7) for gathers.
__global__ __launch_bounds__(256) void k_sortbucket(
        const int* __restrict__ bcnt, unsigned int* __restrict__ arena,
        unsigned short* __restrict__ off16) {
    __shared__ unsigned int s_rec[BSLOTS];
    __shared__ unsigned int s_srt[BSLOTS];
    __shared__ int s_hist[NKEY + 1], s_start[NKEY + 1], s_pos[NKEY];
    int t = threadIdx.x;
    int b = blockIdx.x;

    for (int i = t; i < NKEY + 1; i += 256) s_hist[i] = 0;
    __syncthreads();

    int tot = 0;
#pragma unroll
    for (int p = 0; p < NXCD; ++p) {
        int c = bcnt[b * NXCD + p]; if (c > PSTRIDE) c = PSTRIDE;
        const unsigned int* src = arena + ((size_t)(b * NXCD + p)) * PSTRIDE;
        for (int i = t; i < c; i += 256) {
            unsigned int r = __builtin_nontemporal_load(src + i);
            s_rec[tot + i] = r;
            int key = ((r >> 19) & 127) * 3 + ((r >> 17) & 3);
            atomicAdd(&s_hist[key], 1);
        }
        tot += c;
    }
    __syncthreads();
    if (t == 0) {
        int run = 0;
#pragma unroll 8
        for (int k = 0; k < NKEY; ++k) { s_start[k] = run; run += s_hist[k]; }
        s_start[NKEY] = run;                 // == tot
    }
    __syncthreads();
    for (int i = t; i < NKEY; i += 256) s_pos[i] = s_start[i];
    __syncthreads();
    for (int i = t; i < tot; i += 256) {
        unsigned int r = s_rec[i];
        int key = ((r >> 19) & 127) * 3 + ((r >> 17) & 3);
        int p = atomicAdd(&s_pos[key], 1);
        s_srt[p] = (r & 0x1FFFF) << 7;     // byte offset of src's 128B xbf row
    }
    __syncthreads();
    for (int i = t; i < tot; i += 256)      // coalesced packed writeback at bucket base
        arena[(size_t)b * BSLOTS + i] = s_srt[i];
    for (int i = t; i < NKEY + 1; i += 256)
        off16[(size_t)b * OSTRIDE + i] = (unsigned short)s_start[i];
}

// ---------------- FUSED agg + MFMA transform: K lives in LDS ----------------
// 512 thr = 8 waves = 32 nodes (one strip-pair). Phase 1: wave w aggregates nodes
// w*4+i (R21 gather body) into LDS K rows [32][KST]. Phase 2: wave w = strip (w>>2)
// x h-quadrant (w&3): 8 MFMA with A from LDS, B = W tile (bf16, frag order, same
// k-map). Eliminates the 50MB K write + 51MB K read per layer.
__global__ __launch_bounds__(512) void k_aggxform(
        const unsigned short* __restrict__ xbf,
        const unsigned int* __restrict__ arena,
        const unsigned short* __restrict__ off16,
        const float* __restrict__ wrel, const float* __restrict__ wroot,
        const float* __restrict__ bias,
        float* __restrict__ xout, unsigned short* __restrict__ xbfo) {
    __shared__ __align__(16) unsigned short s_k[NB * KST];
    __shared__ __align__(16) unsigned short s_bf[4][8][64][8];  // [nt][kiter][lane][j]
    __shared__ float s_b[64];
    int t = threadIdx.x;
    // stage W (bf16, fragment order) + bias
    for (int i = t; i < 4 * 8 * 64 * 8; i += 512) {
        int j  = i & 7;
        int l  = (i >> 3) & 63;
        int c  = (i >> 9) & 7;
        int nt = (i >> 12) & 3;
        int k  = c * 32 + (l >> 4) * 8 + j;     // same k-map as the A read below
        int n  = nt * 16 + (l & 15);
        const float* src = (k < 192) ? (wrel + k * 64 + n) : (wroot + (k - 192) * 64 + n);
        s_bf[nt][c][l][j] = f2bf(*src);
    }
    if (t < 64) s_b[t] = bias[t];

    int wave = t >> 6, lane = t & 63;
    int v0 = blockIdx.x * NB;                  // NN % 32 == 0: no tail
    int g = lane >> 4, sl = lane & 15;
    const char* xpb = (const char*)xbf + 8 * sl;   // lane's 4-dim byte base

    // ---- phase 1: aggregate 4 nodes per wave into LDS K rows ----
    for (int i = 0; i < 4; ++i) {
        int lr = wave * 4 + i;
        int v = v0 + lr;
        int b = v >> 7, dlo = v & 127;         // all 32 nodes share one bucket
        const unsigned short* ofs = off16 + (size_t)b * OSTRIDE + dlo * 3;
        int s0 = __builtin_amdgcn_readfirstlane((int)ofs[0]);
        int s1 = __builtin_amdgcn_readfirstlane((int)ofs[1]);
        int s2 = __builtin_amdgcn_readfirstlane((int)ofs[2]);
        int s3 = __builtin_amdgcn_readfirstlane((int)ofs[3]);
        const unsigned int* base = arena + (size_t)b * BSLOTS;

        f32x2 aT0 = {0.f, 0.f}, aT1 = {0.f, 0.f};
        f32x2 a10 = {0.f, 0.f}, a11 = {0.f, 0.f};
        f32x2 a20 = {0.f, 0.f}, a21 = {0.f, 0.f};
        const f32x2 z = {0.f, 0.f};

        int e = s0;
        for (; e + 8 <= s3; e += 8) {
#pragma unroll
            for (int k = 0; k < 2; ++k) {
                int ee = e + 4 * k + g;
                unsigned off = base[ee];                   // pre-scaled byte offset
                uint2 u = *reinterpret_cast<const uint2*>(xpb + off);
                f32x2 f0, f1;
                f0.x = __uint_as_float(u.x << 16);
                f0.y = __uint_as_float(u.x & 0xFFFF0000u);
                f1.x = __uint_as_float(u.y << 16);
                f1.y = __uint_as_float(u.y & 0xFFFF0000u);
                aT0 += f0;  aT1 += f1;
                bool c2 = ee >= s2;
                bool c1 = (ee >= s1) && !c2;
                a10 += c1 ? f0 : z;  a11 += c1 ? f1 : z;
                a20 += c2 ? f0 : z;  a21 += c2 ? f1 : z;
            }
        }
        for (; e < s3; e += 4) {                           // masked tail quad(s)
            int ee = e + g;
            bool ok = ee < s3;
            unsigned off = base[ok ? ee : s3 - 1];
            uint2 u = *reinterpret_cast<const uint2*>(xpb + off);
            if (!ok) { u.x = 0u; u.y = 0u; }
            f32x2 f0, f1;
            f0.x = __uint_as_float(u.x << 16);
            f0.y = __uint_as_float(u.x & 0xFFFF0000u);
            f1.x = __uint_as_float(u.y << 16);
            f1.y = __uint_as_float(u.y & 0xFFFF0000u);
            aT0 += f0;  aT1 += f1;
            bool c2 = ok && (ee >= s2);
            bool c1 = ok && (ee >= s1) && (ee < s2);
            a10 += c1 ? f0 : z;  a11 += c1 ? f1 : z;
            a20 += c2 ? f0 : z;  a21 += c2 ? f1 : z;
        }

#define RED1(V) { V.x += __shfl_xor(V.x, 16); V.y += __shfl_xor(V.y, 16); }
#define RED2(V) { V.x += __shfl_xor(V.x, 32); V.y += __shfl_xor(V.y, 32); }
        RED1(aT0) RED1(aT1) RED1(a10) RED1(a11) RED1(a20) RED1(a21)
        RED2(aT0) RED2(aT1) RED2(a10) RED2(a11) RED2(a20) RED2(a21)
#undef RED1
#undef RED2

        unsigned short* Kv = s_k + lr * KST;
        if (lane < 16) {
            f32x2 b00, b01;
            b00.x = aT0.x - a10.x - a20.x;  b00.y = aT0.y - a10.y - a20.y;
            b01.x = aT1.x - a11.x - a21.x;  b01.y = aT1.y - a11.y - a21.y;
            float i0 = 1.f / fmaxf((float)(s1 - s0), 1.f);
            float i1 = 1.f / fmaxf((float)(s2 - s1), 1.f);
            float i2 = 1.f / fmaxf((float)(s3 - s2), 1.f);
            uint2 p0, p1, p2;
            p0.x = (unsigned)f2bf(b00.x * i0) | ((unsigned)f2bf(b00.y * i0) << 16);
            p0.y = (unsigned)f2bf(b01.x * i0) | ((unsigned)f2bf(b01.y * i0) << 16);
            p1.x = (unsigned)f2bf(a10.x * i1) | ((unsigned)f2bf(a10.y * i1) << 16);
            p1.y = (unsigned)f2bf(a11.x * i1) | ((unsigned)f2bf(a11.y * i1) << 16);
            p2.x = (unsigned)f2bf(a20.x * i2) | ((unsigned)f2bf(a20.y * i2) << 16);
            p2.y = (unsigned)f2bf(a21.x * i2) | ((unsigned)f2bf(a21.y * i2) << 16);
            uint2* Kw = reinterpret_cast<uint2*>(Kv);
            Kw[sl]      = p0;          // dims 4sl..4sl+3 of mean_r0
            Kw[16 + sl] = p1;
            Kw[32 + sl] = p2;
        }
        Kv[192 + lane] = xbf[(size_t)v * 64 + lane];    // exact self copy
    }
    __syncthreads();

    // ---- phase 2: MFMA; wave -> strip sidx = wave>>2, h-quadrant nt = wave&3 ----
    int sidx = wave >> 2, nt = wave & 3;
    const unsigned short* Ka = s_k + (size_t)(sidx * 16 + (lane & 15)) * KST
                                   + (lane >> 4) * 8;
    f32x4 acc = {0.f, 0.f, 0.f, 0.f};
#pragma unroll
    for (int c = 0; c < 8; ++c) {
        bf16x8 a = *reinterpret_cast<const bf16x8*>(Ka + c * 32);
        bf16x8 bb = *reinterpret_cast<const bf16x8*>(&s_bf[nt][c][lane][0]);
        acc = __builtin_amdgcn_mfma_f32_16x16x32_bf16(a, bb, acc, 0, 0, 0);
    }
    int col = lane & 15, rg = (lane >> 4) * 4;
#pragma unroll
    for (int r = 0; r < 4; ++r) {
        float o = fmaxf(acc[r] + s_b[nt * 16 + col], 0.f);
        size_t row = (size_t)(v0 + sidx * 16 + rg + r);
        if (xout) xout[row * 64 + nt * 16 + col] = o;
        if (xbfo) xbfo[row * 64 + nt * 16 + col] = f2bf(o);
    }
}

// ---------------- global mean pool: wave-segmented over sorted batch ----------------
#define POOL_CHUNK 32
__global__ void k_pool(const float* __restrict__ x, const int* __restrict__ batch,
                       float* __restrict__ psum, int* __restrict__ pcnt) {
    int gwid = (blockIdx.x * 256 + threadIdx.x) >> 6;
    int lane = threadIdx.x & 63;
    int v0 = gwid * POOL_CHUNK;
    if (v0 >= NN) return;
    int v1 = v0 + POOL_CHUNK; if (v1 > NN) v1 = NN;
    float acc = 0.f;
    int cnt = 0;
    int gcur = batch[v0];
    for (int v = v0; v < v1; ++v) {
        int g = batch[v];
        if (g != gcur) {
            atomicAdd(&psum[gcur * 64 + lane], acc);
            if (lane == 0) atomicAdd(&pcnt[gcur], cnt);
            acc = 0.f; cnt = 0; gcur = g;
        }
        acc += x[(size_t)v * 64 + lane];
        ++cnt;
    }
    atomicAdd(&psum[gcur * 64 + lane], acc);
    if (lane == 0) atomicAdd(&pcnt[gcur], cnt);
}

__global__ void k_cls(const float* __restrict__ psum, const int* __restrict__ pcnt,
                      const float* __restrict__ w, const float* __restrict__ b,
                      float* __restrict__ out) {
    int gid = blockIdx.x * 256 + threadIdx.x;
    if (gid >= NG * 10) return;
    int g = gid / 10, c = gid % 10;
    float inv = 1.f / fmaxf((float)pcnt[g], 1.f);
    float acc = 0.f;
#pragma unroll
    for (int d = 0; d < 64; ++d) acc += psum[g * 64 + d] * w[d * 10 + c];
    out[gid] = acc * inv + b[c];
}

extern "C" void kernel_launch(void* const* d_in, const int* in_sizes, int n_in,
                              void* d_out, int out_size, void* d_ws, size_t ws_size,
                              hipStream_t stream) {
    const int*   x_idx  = (const int*)d_in[0];
    const int*   ei     = (const int*)d_in[1];
    const int*   et     = (const int*)d_in[2];
    const int*   batch  = (const int*)d_in[3];
    const float* semb   = (const float*)d_in[4];
    const float* cemb   = (const float*)d_in[5];
    const float* lin0w  = (const float*)d_in[6];
    const float* lin0b  = (const float*)d_in[7];
    const float* r1wrel = (const float*)d_in[8];
    const float* r1wroot= (const float*)d_in[9];
    const float* r1b    = (const float*)d_in[10];
    const float* r2wrel = (const float*)d_in[11];
    const float* r2wroot= (const float*)d_in[12];
    const float* r2b    = (const float*)d_in[13];
    const float* clsw   = (const float*)d_in[14];
    const float* clsb   = (const float*)d_in[15];
    float* out = (float*)d_out;

    char* ws = (char*)d_ws;
    size_t o = 0;
    auto alloc = [&](size_t bytes) -> void* {
        void* p = ws + o;
        o += (bytes + 255) & ~(size_t)255;
        return p;
    };
    int*            bcnt  = (int*)           alloc((size_t)NBUCK * NXCD * 4);
    unsigned int*   arena = (unsigned int*)  alloc((size_t)NBUCK * BSLOTS * 4);
    unsigned short* off16 = (unsigned short*)alloc((size_t)NBUCK * OSTRIDE * 2);
    float*          xA    = (float*)         alloc((size_t)NN * 64 * 4);
    unsigned short* xbf   = (unsigned short*)alloc((size_t)NN * 64 * 2);    // embed out
    unsigned short* xbf2  = (unsigned short*)alloc((size_t)NN * 64 * 2);    // layer-1 out
    float*          psum  = (float*)         alloc((size_t)NG * 64 * 4);
    int*            pcnt  = (int*)           alloc((size_t)NG * 4);

    hipMemsetAsync(bcnt, 0, (size_t)NBUCK * NXCD * 4, stream);
    hipMemsetAsync(psum, 0, (size_t)NG * 64 * 4, stream);
    hipMemsetAsync(pcnt, 0, (size_t)NG * 4, stream);

    // node features (bf16 mirror only)
    k_embed<<<NN * 64 / 256, 256, 0, stream>>>(x_idx, semb, cemb, lin0w, lin0b, xbf);

    // bucket build (LDS-binned, XCD-private) + per-bucket counting sort (once, both layers)
    k_bucket<<<(NE + EB - 1) / EB, 256, 0, stream>>>(ei, et, bcnt, arena);
    k_sortbucket<<<NBUCK, 256, 0, stream>>>(bcnt, arena, off16);

    // layer 1 (fused agg+transform; mirror out)
    k_aggxform<<<NN / NB, 512, 0, stream>>>(xbf, arena, off16, r1wrel, r1wroot, r1b,
                                            (float*)nullptr, xbf2);
    // layer 2 (fused; f32 out for pool)
    k_aggxform<<<NN / NB, 512, 0, stream>>>(xbf2, arena, off16, r2wrel, r2wroot, r2b,
                                            xA, (unsigned short*)nullptr);

    // pool + classify
    {
        int nwaves = (NN + POOL_CHUNK - 1) / POOL_CHUNK;        // 3125
        int nblk = (nwaves * 64 + 255) / 256;                   // 782
        k_pool<<<nblk, 256, 0, stream>>>(xA, batch, psum, pcnt);
    }
    k_cls<<<(NG * 10 + 255) / 256, 256, 0, stream>>>(psum, pcnt, clsw, clsb, out);
}

// Round 23
// 284.384 us; speedup vs baseline: 1.1728x; 1.1728x over previous
//
#include <hip/hip_runtime.h>

#define NN 100000        // nodes
#define NE 1600000       // edges
#define NRL 3            // relations
#define NG 1024          // graphs
#define NBUCK 782        // ceil(NN/128) buckets of 128 nodes
#define NXCD 8
#define PSTRIDE 384      // slots per (bucket, xcd): mean 256, sigma 16 -> +8 sigma
#define BSLOTS (NXCD * PSTRIDE)   // 3072 slots per bucket
#define NKEY 384         // 128 nodes * 3 rel
#define OSTRIDE 392      // u16 offsets per bucket (384 starts + total, padded)
#define EB 4096          // edges per k_bucket block

typedef __attribute__((ext_vector_type(8))) short bf16x8;
typedef __attribute__((ext_vector_type(4))) float f32x4;
typedef __attribute__((ext_vector_type(2))) float f32x2;

__device__ __forceinline__ int xcd_id() {
    unsigned int x;
    asm volatile("s_getreg_b32 %0, hwreg(HW_REG_XCC_ID)" : "=s"(x));
    return (int)(x & 7);
}

// f32 -> bf16 with round-to-nearest-even
__device__ __forceinline__ unsigned short f2bf(float f) {
    unsigned u = __float_as_uint(f);
    unsigned r = (u + 0x7fffu + ((u >> 16) & 1u)) >> 16;
    return (unsigned short)r;
}

// ---------------- embed + lin0 + relu (bf16 mirror only; f32 x never read) ----------------
__global__ void k_embed(const int* __restrict__ x_idx,
                        const float* __restrict__ semb, const float* __restrict__ cemb,
                        const float* __restrict__ w, const float* __restrict__ b,
                        unsigned short* __restrict__ xbf) {
    __shared__ float s_w[16 * 64];
    __shared__ float s_se[64], s_ce[64], s_b[64];
    int t = threadIdx.x;
    for (int i = t; i < 16 * 64; i += 256) s_w[i] = w[i];
    if (t < 64) { s_se[t] = semb[t]; s_ce[t] = cemb[t]; s_b[t] = b[t]; }
    __syncthreads();
    int gid = blockIdx.x * 256 + t;           // grid exactly NN*64/256
    int v = gid >> 6, h = gid & 63;
    int si = x_idx[2 * v], ci = x_idx[2 * v + 1];
    float acc = s_b[h];
#pragma unroll
    for (int d = 0; d < 8; ++d) acc += s_se[si * 8 + d] * s_w[d * 64 + h];
#pragma unroll
    for (int d = 0; d < 8; ++d) acc += s_ce[ci * 8 + d] * s_w[(8 + d) * 64 + h];
    xbf[gid] = f2bf(fmaxf(acc, 0.f));
}

// ---------------- bucket build: LDS-binned, run-coalesced writeback ----------------
// rec = src (17b) | rel<<17 (2b) | (dst&127)<<19 (7b)
__global__ __launch_bounds__(256) void k_bucket(
        const int* __restrict__ ei, const int* __restrict__ et,
        int* __restrict__ bcnt, unsigned int* __restrict__ arena) {
    __shared__ unsigned int   s_srt[EB];
    __shared__ unsigned short s_skey[EB];
    __shared__ int s_hist[NBUCK], s_start[NBUCK + 1], s_base[NBUCK], s_pos[NBUCK];
    int t = threadIdx.x;
    int e0 = blockIdx.x * EB;
    int n = NE - e0; if (n > EB) n = EB;
    int p = xcd_id();                              // block-uniform (block lives on 1 CU)

    for (int i = t; i < NBUCK; i += 256) s_hist[i] = 0;
    __syncthreads();

    // pass 1: histogram buckets
    for (int i = t; i < n; i += 256) {
        int dst = __builtin_nontemporal_load(ei + NE + e0 + i);
        atomicAdd(&s_hist[dst >> 7], 1);
    }
    __syncthreads();
    if (t == 0) {
        int run = 0;
#pragma unroll 8
        for (int k = 0; k < NBUCK; ++k) { s_start[k] = run; run += s_hist[k]; }
        s_start[NBUCK] = run;
    }
    __syncthreads();
    // reserve global runs (one atomic per non-empty bucket)
    for (int k = t; k < NBUCK; k += 256) {
        s_pos[k] = s_start[k];
        s_base[k] = (s_hist[k] > 0) ? atomicAdd(&bcnt[k * NXCD + p], s_hist[k]) : 0;
    }
    __syncthreads();

    // pass 2: scatter records into LDS in bucket-sorted order
    for (int i = t; i < n; i += 256) {
        int e = e0 + i;
        int src = __builtin_nontemporal_load(ei + e);
        int dst = __builtin_nontemporal_load(ei + NE + e);
        int rel = __builtin_nontemporal_load(et + e);
        int key = dst >> 7;
        unsigned int rec = (unsigned int)src | ((unsigned int)rel << 17) |
                           ((unsigned int)(dst & 127) << 19);
        int q = atomicAdd(&s_pos[key], 1);
        s_srt[q] = rec;
        s_skey[q] = (unsigned short)key;
    }
    __syncthreads();

    // coalesced writeback: sorted index i -> arena[(key,xcd) partition, base + rank]
    for (int i = t; i < n; i += 256) {
        int key = (int)s_skey[i];
        int off = s_base[key] + (i - s_start[key]);
        if (off < PSTRIDE)
            arena[((size_t)key * NXCD + p) * PSTRIDE + off] = s_srt[i];
    }
}

// ---------------- per-bucket LDS counting sort: 8 partitions -> sorted offsets ----------------
// key = dstlo*3 + rel (384 keys). Stores PRE-SCALED byte offsets (src<<7) for k_agg.
__global__ __launch_bounds__(256) void k_sortbucket(
        const int* __restrict__ bcnt, unsigned int* __restrict__ arena,
        unsigned short* __restrict__ off16) {
    __shared__ unsigned int s_rec[BSLOTS];
    __shared__ unsigned int s_srt[BSLOTS];
    __shared__ int s_hist[NKEY + 1], s_start[NKEY + 1], s_pos[NKEY];
    int t = threadIdx.x;
    int b = blockIdx.x;

    for (int i = t; i < NKEY + 1; i += 256) s_hist[i] = 0;
    __syncthreads();

    int tot = 0;
#pragma unroll
    for (int p = 0; p < NXCD; ++p) {
        int c = bcnt[b * NXCD + p]; if (c > PSTRIDE) c = PSTRIDE;
        const unsigned int* src = arena + ((size_t)(b * NXCD + p)) * PSTRIDE;
        for (int i = t; i < c; i += 256) {
            unsigned int r = __builtin_nontemporal_load(src + i);
            s_rec[tot + i] = r;
            int key = ((r >> 19) & 127) * 3 + ((r >> 17) & 3);
            atomicAdd(&s_hist[key], 1);
        }
        tot += c;
    }
    __syncthreads();
    if (t == 0) {
        int run = 0;
#pragma unroll 8
        for (int k = 0; k < NKEY; ++k) { s_start[k] = run; run += s_hist[k]; }
        s_start[NKEY] = run;                 // == tot
    }
    __syncthreads();
    for (int i = t; i < NKEY; i += 256) s_pos[i] = s_start[i];
    __syncthreads();
    for (int i = t; i < tot; i += 256) {
        unsigned int r = s_rec[i];
        int key = ((r >> 19) & 127) * 3 + ((r >> 17) & 3);
        int p = atomicAdd(&s_pos[key], 1);
        s_srt[p] = (r & 0x1FFFF) << 7;     // byte offset of src's 128B xbf row
    }
    __syncthreads();
    for (int i = t; i < tot; i += 256)      // coalesced packed writeback at bucket base
        arena[(size_t)b * BSLOTS + i] = s_srt[i];
    for (int i = t; i < NKEY + 1; i += 256)
        off16[(size_t)b * OSTRIDE + i] = (unsigned short)s_start[i];
}

// ---------------- per-(r,dst) mean aggregation: 4 edges per gather instruction ----------------
// Lane groups of 16: group g covers edge e+g; lane holds dims 4sl..4sl+3 via one
// dwordx2 at (src<<7)+8*sl -> each gather moves 4 full 128B rows; idx loads cover
// 4 edges. Cross-group reduce: shfl_xor 16,32. Subtract trick for segment 0.
__global__ void k_agg(const unsigned short* __restrict__ xbf,
                      const unsigned int* __restrict__ arena,
                      const unsigned short* __restrict__ off16,
                      unsigned short* __restrict__ K) {
    int wid = (blockIdx.x * 256 + threadIdx.x) >> 6;
    int lane = threadIdx.x & 63;
    if (wid >= NN) return;
    int v = wid;
    int b = v >> 7, dlo = v & 127;
    const unsigned short* ofs = off16 + (size_t)b * OSTRIDE + dlo * 3;
    int s0 = __builtin_amdgcn_readfirstlane((int)ofs[0]);
    int s1 = __builtin_amdgcn_readfirstlane((int)ofs[1]);
    int s2 = __builtin_amdgcn_readfirstlane((int)ofs[2]);
    int s3 = __builtin_amdgcn_readfirstlane((int)ofs[3]);
    const unsigned int* base = arena + (size_t)b * BSLOTS;

    int g = lane >> 4, sl = lane & 15;
    const char* xpb = (const char*)xbf + 8 * sl;   // lane's 4-dim byte base

    f32x2 aT0 = {0.f, 0.f}, aT1 = {0.f, 0.f};
    f32x2 a10 = {0.f, 0.f}, a11 = {0.f, 0.f};
    f32x2 a20 = {0.f, 0.f}, a21 = {0.f, 0.f};
    const f32x2 z = {0.f, 0.f};

    int e = s0;
    for (; e + 8 <= s3; e += 8) {
#pragma unroll
        for (int k = 0; k < 2; ++k) {
            int ee = e + 4 * k + g;
            unsigned off = base[ee];                       // pre-scaled byte offset
            uint2 u = *reinterpret_cast<const uint2*>(xpb + off);
            f32x2 f0, f1;
            f0.x = __uint_as_float(u.x << 16);             // dim 4sl
            f0.y = __uint_as_float(u.x & 0xFFFF0000u);     // dim 4sl+1
            f1.x = __uint_as_float(u.y << 16);             // dim 4sl+2
            f1.y = __uint_as_float(u.y & 0xFFFF0000u);     // dim 4sl+3
            aT0 += f0;  aT1 += f1;                         // v_pk_add_f32
            bool c2 = ee >= s2;
            bool c1 = (ee >= s1) && !c2;
            a10 += c1 ? f0 : z;  a11 += c1 ? f1 : z;
            a20 += c2 ? f0 : z;  a21 += c2 ? f1 : z;
        }
    }
    for (; e < s3; e += 4) {                               // masked tail quad(s)
        int ee = e + g;
        bool ok = ee < s3;
        unsigned off = base[ok ? ee : s3 - 1];
        uint2 u = *reinterpret_cast<const uint2*>(xpb + off);
        if (!ok) { u.x = 0u; u.y = 0u; }
        f32x2 f0, f1;
        f0.x = __uint_as_float(u.x << 16);
        f0.y = __uint_as_float(u.x & 0xFFFF0000u);
        f1.x = __uint_as_float(u.y << 16);
        f1.y = __uint_as_float(u.y & 0xFFFF0000u);
        aT0 += f0;  aT1 += f1;
        bool c2 = ok && (ee >= s2);
        bool c1 = ok && (ee >= s1) && (ee < s2);
        a10 += c1 ? f0 : z;  a11 += c1 ? f1 : z;
        a20 += c2 ? f0 : z;  a21 += c2 ? f1 : z;
    }

    // reduce across the 4 edge-groups (lanes sl, sl+16, sl+32, sl+48)
#define RED1(V) { V.x += __shfl_xor(V.x, 16); V.y += __shfl_xor(V.y, 16); }
#define RED2(V) { V.x += __shfl_xor(V.x, 32); V.y += __shfl_xor(V.y, 32); }
    RED1(aT0) RED1(aT1) RED1(a10) RED1(a11) RED1(a20) RED1(a21)
    RED2(aT0) RED2(aT1) RED2(a10) RED2(a11) RED2(a20) RED2(a21)
#undef RED1
#undef RED2

    unsigned short* Kv = K + (size_t)v * 256;
    if (lane < 16) {
        f32x2 b00, b01;
        b00.x = aT0.x - a10.x - a20.x;  b00.y = aT0.y - a10.y - a20.y;
        b01.x = aT1.x - a11.x - a21.x;  b01.y = aT1.y - a11.y - a21.y;
        float i0 = 1.f / fmaxf((float)(s1 - s0), 1.f);     // 3 uniform reciprocals
        float i1 = 1.f / fmaxf((float)(s2 - s1), 1.f);
        float i2 = 1.f / fmaxf((float)(s3 - s2), 1.f);
        uint2 p0, p1, p2;
        p0.x = (unsigned)f2bf(b00.x * i0) | ((unsigned)f2bf(b00.y * i0) << 16);
        p0.y = (unsigned)f2bf(b01.x * i0) | ((unsigned)f2bf(b01.y * i0) << 16);
        p1.x = (unsigned)f2bf(a10.x * i1) | ((unsigned)f2bf(a10.y * i1) << 16);
        p1.y = (unsigned)f2bf(a11.x * i1) | ((unsigned)f2bf(a11.y * i1) << 16);
        p2.x = (unsigned)f2bf(a20.x * i2) | ((unsigned)f2bf(a20.y * i2) << 16);
        p2.y = (unsigned)f2bf(a21.x * i2) | ((unsigned)f2bf(a21.y * i2) << 16);
        uint2* Kw = reinterpret_cast<uint2*>(Kv);
        Kw[sl]      = p0;          // dims 4sl..4sl+3 of mean_r0
        Kw[16 + sl] = p1;
        Kw[32 + sl] = p2;
    }
    Kv[192 + lane] = xbf[(size_t)v * 64 + lane];    // exact self copy
}

// ---------------- dense transform via MFMA: xout = relu(K @ [Wr;Wroot] + b) ----------------
// v_mfma_f32_16x16x32_bf16. Wave = 16-node strip x 64 h (4 C-tiles). 8 K-iters of 32.
// xout (f32) and xbf (bf16 mirror) both optional: layer1 writes mirror only,
// layer2 writes f32 only (pool consumes it).
__global__ __launch_bounds__(512, 4) void k_transform(
        const unsigned short* __restrict__ K, const float* __restrict__ wrel,
        const float* __restrict__ wroot, const float* __restrict__ b,
        float* __restrict__ xout, unsigned short* __restrict__ xbf) {
    __shared__ __align__(16) unsigned short s_bf[4][8][64][8];  // [ntile][kiter][lane][j]
    __shared__ float s_b[64];
    int t = threadIdx.x;
    for (int i = t; i < 4 * 8 * 64 * 8; i += 512) {
        int j  = i & 7;
        int l  = (i >> 3) & 63;
        int c  = (i >> 9) & 7;
        int nt = (i >> 12) & 3;
        int k  = c * 32 + (l >> 4) * 8 + j;     // same k-map as the A load below
        int n  = nt * 16 + (l & 15);
        const float* src = (k < 192) ? (wrel + k * 64 + n) : (wroot + (k - 192) * 64 + n);
        s_bf[nt][c][l][j] = f2bf(*src);
    }
    if (t < 64) s_b[t] = b[t];
    __syncthreads();

    int wave = t >> 6, lane = t & 63;
    int strip = blockIdx.x * 8 + wave;
    if (strip > NN / 16 - 1) strip = NN / 16 - 1;   // dup strips write identical data
    int v0 = strip * 16;

    const unsigned short* Ka = K + (size_t)(v0 + (lane & 15)) * 256 + (lane >> 4) * 8;

    f32x4 acc0 = {0.f, 0.f, 0.f, 0.f};
    f32x4 acc1 = {0.f, 0.f, 0.f, 0.f};
    f32x4 acc2 = {0.f, 0.f, 0.f, 0.f};
    f32x4 acc3 = {0.f, 0.f, 0.f, 0.f};

#pragma unroll
    for (int c = 0; c < 8; ++c) {
        bf16x8 a = *reinterpret_cast<const bf16x8*>(Ka + c * 32);
        bf16x8 b0 = *reinterpret_cast<const bf16x8*>(&s_bf[0][c][lane][0]);
        bf16x8 b1 = *reinterpret_cast<const bf16x8*>(&s_bf[1][c][lane][0]);
        bf16x8 b2 = *reinterpret_cast<const bf16x8*>(&s_bf[2][c][lane][0]);
        bf16x8 b3 = *reinterpret_cast<const bf16x8*>(&s_bf[3][c][lane][0]);
        acc0 = __builtin_amdgcn_mfma_f32_16x16x32_bf16(a, b0, acc0, 0, 0, 0);
        acc1 = __builtin_amdgcn_mfma_f32_16x16x32_bf16(a, b1, acc1, 0, 0, 0);
        acc2 = __builtin_amdgcn_mfma_f32_16x16x32_bf16(a, b2, acc2, 0, 0, 0);
        acc3 = __builtin_amdgcn_mfma_f32_16x16x32_bf16(a, b3, acc3, 0, 0, 0);
    }

    int col = lane & 15, rg = (lane >> 4) * 4;
#pragma unroll
    for (int r = 0; r < 4; ++r) {
        float o0 = fmaxf(acc0[r] + s_b[0  + col], 0.f);
        float o1 = fmaxf(acc1[r] + s_b[16 + col], 0.f);
        float o2 = fmaxf(acc2[r] + s_b[32 + col], 0.f);
        float o3 = fmaxf(acc3[r] + s_b[48 + col], 0.f);
        if (xout) {
            float* op = xout + (size_t)(v0 + rg + r) * 64;
            op[0  + col] = o0;
            op[16 + col] = o1;
            op[32 + col] = o2;
            op[48 + col] = o3;
        }
        if (xbf) {
            unsigned short* ob = xbf + (size_t)(v0 + rg + r) * 64;
            ob[0  + col] = f2bf(o0);
            ob[16 + col] = f2bf(o1);
            ob[32 + col] = f2bf(o2);
            ob[48 + col] = f2bf(o3);
        }
    }
}

// ---------------- global mean pool: wave-segmented over sorted batch ----------------
#define POOL_CHUNK 32
__global__ void k_pool(const float* __restrict__ x, const int* __restrict__ batch,
                       float* __restrict__ psum, int* __restrict__ pcnt) {
    int gwid = (blockIdx.x * 256 + threadIdx.x) >> 6;
    int lane = threadIdx.x & 63;
    int v0 = gwid * POOL_CHUNK;
    if (v0 >= NN) return;
    int v1 = v0 + POOL_CHUNK; if (v1 > NN) v1 = NN;
    float acc = 0.f;
    int cnt = 0;
    int gcur = batch[v0];
    for (int v = v0; v < v1; ++v) {
        int g = batch[v];
        if (g != gcur) {
            atomicAdd(&psum[gcur * 64 + lane], acc);
            if (lane == 0) atomicAdd(&pcnt[gcur], cnt);
            acc = 0.f; cnt = 0; gcur = g;
        }
        acc += x[(size_t)v * 64 + lane];
        ++cnt;
    }
    atomicAdd(&psum[gcur * 64 + lane], acc);
    if (lane == 0) atomicAdd(&pcnt[gcur], cnt);
}

__global__ void k_cls(const float* __restrict__ psum, const int* __restrict__ pcnt,
                      const float* __restrict__ w, const float* __restrict__ b,
                      float* __restrict__ out) {
    int gid = blockIdx.x * 256 + threadIdx.x;
    if (gid >= NG * 10) return;
    int g = gid / 10, c = gid % 10;
    float inv = 1.f / fmaxf((float)pcnt[g], 1.f);
    float acc = 0.f;
#pragma unroll
    for (int d = 0; d < 64; ++d) acc += psum[g * 64 + d] * w[d * 10 + c];
    out[gid] = acc * inv + b[c];
}

extern "C" void kernel_launch(void* const* d_in, const int* in_sizes, int n_in,
                              void* d_out, int out_size, void* d_ws, size_t ws_size,
                              hipStream_t stream) {
    const int*   x_idx  = (const int*)d_in[0];
    const int*   ei     = (const int*)d_in[1];
    const int*   et     = (const int*)d_in[2];
    const int*   batch  = (const int*)d_in[3];
    const float* semb   = (const float*)d_in[4];
    const float* cemb   = (const float*)d_in[5];
    const float* lin0w  = (const float*)d_in[6];
    const float* lin0b  = (const float*)d_in[7];
    const float* r1wrel = (const float*)d_in[8];
    const float* r1wroot= (const float*)d_in[9];
    const float* r1b    = (const float*)d_in[10];
    const float* r2wrel = (const float*)d_in[11];
    const float* r2wroot= (const float*)d_in[12];
    const float* r2b    = (const float*)d_in[13];
    const float* clsw   = (const float*)d_in[14];
    const float* clsb   = (const float*)d_in[15];
    float* out = (float*)d_out;

    char* ws = (char*)d_ws;
    size_t o = 0;
    auto alloc = [&](size_t bytes) -> void* {
        void* p = ws + o;
        o += (bytes + 255) & ~(size_t)255;
        return p;
    };
    int*            bcnt  = (int*)           alloc((size_t)NBUCK * NXCD * 4);
    unsigned int*   arena = (unsigned int*)  alloc((size_t)NBUCK * BSLOTS * 4);
    unsigned short* off16 = (unsigned short*)alloc((size_t)NBUCK * OSTRIDE * 2);
    float*          xA    = (float*)         alloc((size_t)NN * 64 * 4);
    unsigned short* xbf   = (unsigned short*)alloc((size_t)NN * 64 * 2);    // bf16 mirror
    unsigned short* Kbuf  = (unsigned short*)alloc((size_t)NN * 256 * 2);   // bf16
    float*          psum  = (float*)         alloc((size_t)NG * 64 * 4);
    int*            pcnt  = (int*)           alloc((size_t)NG * 4);

    hipMemsetAsync(bcnt, 0, (size_t)NBUCK * NXCD * 4, stream);
    hipMemsetAsync(psum, 0, (size_t)NG * 64 * 4, stream);
    hipMemsetAsync(pcnt, 0, (size_t)NG * 4, stream);

    // node features (bf16 mirror only)
    k_embed<<<NN * 64 / 256, 256, 0, stream>>>(x_idx, semb, cemb, lin0w, lin0b, xbf);

    // bucket build (LDS-binned, XCD-private) + per-bucket counting sort (once, both layers)
    k_bucket<<<(NE + EB - 1) / EB, 256, 0, stream>>>(ei, et, bcnt, arena);
    k_sortbucket<<<NBUCK, 256, 0, stream>>>(bcnt, arena, off16);

    // layer 1 (mirror only)
    k_agg<<<NN / 4, 256, 0, stream>>>(xbf, arena, off16, Kbuf);
    k_transform<<<(NN / 16 + 7) / 8, 512, 0, stream>>>(Kbuf, r1wrel, r1wroot, r1b,
                                                       (float*)nullptr, xbf);
    // layer 2 (f32 out for pool)
    k_agg<<<NN / 4, 256, 0, stream>>>(xbf, arena, off16, Kbuf);
    k_transform<<<(NN / 16 + 7) / 8, 512, 0, stream>>>(Kbuf, r2wrel, r2wroot, r2b, xA,
                                                       (unsigned short*)nullptr);

    // pool + classify
    {
        int nwaves = (NN + POOL_CHUNK - 1) / POOL_CHUNK;        // 3125
        int nblk = (nwaves * 64 + 255) / 256;                   // 782
        k_pool<<<nblk, 256, 0, stream>>>(xA, batch, psum, pcnt);
    }
    k_cls<<<(NG * 10 + 255) / 256, 256, 0, stream>>>(psum, pcnt, clsw, clsb, out);
}